// Round 2
// baseline (356.599 us; speedup 1.0000x reference)
//
#include <hip/hip_runtime.h>
#include <math.h>

#define LSEQ 4096
#define NFFT 8192
#define NF   512     // kept frequency bins
#define NF2  1024    // 2*NF (cos/sin interleaved)
#define NH   768
#define NBH  6144    // 8*768
#define MROWS 6912   // NBH + NH (x rows + k rows share stage-A GEMM)

typedef __attribute__((ext_vector_type(8))) short short8;   // 8 bf16 (4 VGPRs)
typedef __attribute__((ext_vector_type(4))) float floatx4;  // MFMA accumulator

__device__ __forceinline__ unsigned short f2bf(float f) {
    unsigned int u = __float_as_uint(f);
    u += 0x7fff + ((u >> 16) & 1);       // round-to-nearest-even
    return (unsigned short)(u >> 16);
}

// direct HBM->LDS async copy, 16B per lane (global_load_lds_dwordx4).
// LDS dest is wave-uniform base + lane*16; global src is per-lane.
__device__ __forceinline__ void gld16(const unsigned short* g, unsigned short* l) {
    __builtin_amdgcn_global_load_lds(
        (const __attribute__((address_space(1))) void*)g,
        (__attribute__((address_space(3))) void*)l, 16, 0, 0);
}

// -------- fused trig tables: T1[f2][n] and T2[n][f2], bf16 -----------------
__global__ void build_tables(unsigned short* __restrict__ T1,
                             unsigned short* __restrict__ T2) {
    __shared__ unsigned short tile[64][66];   // pad 66: transpose-read conflict-free
    const int t = threadIdx.x;
    const int F0 = blockIdx.x * 64;
    const int N0 = blockIdx.y * 64;
#pragma unroll
    for (int i = 0; i < 16; ++i) {
        int r = (t >> 6) + i * 4;
        int c = t & 63;
        int f2 = F0 + r, n = N0 + c;
        int f = f2 >> 1;
        int p = (f * n) & (NFFT - 1);
        float th = (float)p * (float)(2.0 * M_PI / (double)NFFT);
        float s, cc;
        sincosf(th, &s, &cc);
        unsigned short v = f2bf((f2 & 1) ? s : cc);
        T1[(size_t)f2 * LSEQ + n] = v;
        tile[r][c] = v;
    }
    __syncthreads();
#pragma unroll
    for (int i = 0; i < 16; ++i) {
        int r = (t >> 6) + i * 4;
        int c = t & 63;
        T2[(size_t)(N0 + r) * NF2 + F0 + c] = tile[c][r];
    }
}

// -------- fp32 -> bf16 pack of [x ; k] into one [6912, 4096] matrix --------
__global__ void tobf16(const float* __restrict__ x, const float* __restrict__ kk,
                       unsigned short* __restrict__ o) {
    size_t e = ((size_t)blockIdx.x * 256 + threadIdx.x) * 4;
    const size_t XN = (size_t)NBH * LSEQ;
    const float* s = (e < XN) ? (x + e) : (kk + (e - XN));
    float4 v = *(const float4*)s;
    unsigned int lo = (unsigned int)f2bf(v.x) | ((unsigned int)f2bf(v.y) << 16);
    unsigned int hi = (unsigned int)f2bf(v.z) | ((unsigned int)f2bf(v.w) << 16);
    *(uint2*)(o + e) = make_uint2(lo, hi);
}

// -------- m97-structure bf16 GEMM: C[M,N] = A[M,K] * B^T[N,K], fp32 out ----
// R1: reg-staging (global->VGPR->ds_write) was VALUBusy=32% with only ~7
// waves/CU to hide it (grid-capped occupancy).  Switch staging to
// global_load_lds_dwordx4 (direct HBM->LDS, no VGPR round-trip, no ds_write):
// per K-iter each wave issues 4 chunk loads (wave-uniform LDS base, per-lane
// global src), then ds_read+MFMA on the other buffer, one barrier per iter
// (barrier's vmcnt(0) drain doubles as the load fence).  m151: 646->874 TF
// for exactly this swap at 128^2 tiles.
__global__ __launch_bounds__(256) void gemm_bt(
    const unsigned short* __restrict__ A,   // [M,K] bf16
    const unsigned short* __restrict__ B,   // [N,K] bf16 (transposed operand)
    float* __restrict__ C,                  // [M,N] fp32
    int M, int N, int K)
{
    __shared__ __align__(16) unsigned short As[2][128 * 32];
    __shared__ __align__(16) unsigned short Bs[2][128 * 32];
    const int t = threadIdx.x;
    const int w = t >> 6, l = t & 63;
    const int m0 = blockIdx.y * 128, n0 = blockIdx.x * 128;
    const int wm = (w >> 1) * 64, wn = (w & 1) * 64;
    const int lq = l >> 4, lr = l & 15;

    floatx4 acc[4][4];
#pragma unroll
    for (int i = 0; i < 4; ++i)
#pragma unroll
        for (int j = 0; j < 4; ++j)
            acc[i][j] = (floatx4){0.f, 0.f, 0.f, 0.f};

    // staging geometry: tile half (A or B) = 128 rows x 32 cols = 8 KB
    // = 8 chunks of 16 rows (1 KB = 64 lanes x 16 B).  Wave w owns chunks
    // {2w, 2w+1} of each operand -> 4 gld16 per wave per K-iter.
    const int sr = l >> 2, se = (l & 3) * 8;       // lane's row-in-chunk, col
    const int c0 = 2 * w, c1 = 2 * w + 1;
    const unsigned short* gA0 = A + (size_t)(m0 + c0 * 16 + sr) * K + se;
    const unsigned short* gA1 = A + (size_t)(m0 + c1 * 16 + sr) * K + se;
    const unsigned short* gB0 = B + (size_t)(n0 + c0 * 16 + sr) * K + se;
    const unsigned short* gB1 = B + (size_t)(n0 + c1 * 16 + sr) * K + se;

    // prologue: tile 0 -> LDS buf0
    gld16(gA0, As[0] + c0 * 512);
    gld16(gA1, As[0] + c1 * 512);
    gld16(gB0, Bs[0] + c0 * 512);
    gld16(gB1, Bs[0] + c1 * 512);
    __syncthreads();   // compiler emits vmcnt(0) drain before s_barrier

    int cur = 0;
    for (int k0 = 32; k0 < K; k0 += 32) {
        // issue next tile's loads into the other buffer (in flight across
        // the ds_read+MFMA phase; fenced by the barrier's vmcnt(0) drain)
        const int nxt = cur ^ 1;
        gld16(gA0 + k0, As[nxt] + c0 * 512);
        gld16(gA1 + k0, As[nxt] + c1 * 512);
        gld16(gB0 + k0, Bs[nxt] + c0 * 512);
        gld16(gB1 + k0, Bs[nxt] + c1 * 512);

        short8 af[4], bfv[4];
#pragma unroll
        for (int i = 0; i < 4; ++i)
            af[i] = *(const short8*)(As[cur] + (wm + 16 * i + lr) * 32 + lq * 8);
#pragma unroll
        for (int j = 0; j < 4; ++j)
            bfv[j] = *(const short8*)(Bs[cur] + (wn + 16 * j + lr) * 32 + lq * 8);
#pragma unroll
        for (int i = 0; i < 4; ++i)
#pragma unroll
            for (int j = 0; j < 4; ++j)
                acc[i][j] = __builtin_amdgcn_mfma_f32_16x16x32_bf16(af[i], bfv[j], acc[i][j], 0, 0, 0);

        __syncthreads();
        cur = nxt;
    }

    // last tile
    {
        short8 af[4], bfv[4];
#pragma unroll
        for (int i = 0; i < 4; ++i)
            af[i] = *(const short8*)(As[cur] + (wm + 16 * i + lr) * 32 + lq * 8);
#pragma unroll
        for (int j = 0; j < 4; ++j)
            bfv[j] = *(const short8*)(Bs[cur] + (wn + 16 * j + lr) * 32 + lq * 8);
#pragma unroll
        for (int i = 0; i < 4; ++i)
#pragma unroll
            for (int j = 0; j < 4; ++j)
                acc[i][j] = __builtin_amdgcn_mfma_f32_16x16x32_bf16(af[i], bfv[j], acc[i][j], 0, 0, 0);
    }

    // C/D layout: col = lane&15, row = (lane>>4)*4 + reg  [verified m89/m91]
#pragma unroll
    for (int i = 0; i < 4; ++i)
#pragma unroll
        for (int j = 0; j < 4; ++j)
#pragma unroll
            for (int r = 0; r < 4; ++r) {
                int row = m0 + wm + 16 * i + lq * 4 + r;
                int col = n0 + wn + 16 * j + lr;
                C[(size_t)row * N + col] = acc[i][j][r];
            }
}

// -------- combine: complex multiply + irfft scaling -> bf16 AB -------------
__global__ void combine(const float* __restrict__ C1, unsigned short* __restrict__ AB) {
    int idx = blockIdx.x * blockDim.x + threadIdx.x;   // bh*512 + f
    int bh = idx >> 9;
    int f = idx & (NF - 1);
    int h = bh % NH;
    const float* xc = C1 + (size_t)bh * NF2 + 2 * f;
    const float* kc = C1 + (size_t)(NBH + h) * NF2 + 2 * f;
    float Xre = xc[0], Xim = -xc[1];
    float Kre = kc[0], Kim = -kc[1];
    float s = (f == 0 ? 1.0f : 2.0f) * (1.0f / (float)NFFT);
    float Av = s * (Xre * Kre - Xim * Kim);
    float Bv = -(s * (Xre * Kim + Xim * Kre));
    unsigned int packed = (unsigned int)f2bf(Av) | ((unsigned int)f2bf(Bv) << 16);
    *(unsigned int*)(AB + (size_t)bh * NF2 + 2 * f) = packed;
}

extern "C" void kernel_launch(void* const* d_in, const int* in_sizes, int n_in,
                              void* d_out, int out_size, void* d_ws, size_t ws_size,
                              hipStream_t stream) {
    const float* x = (const float*)d_in[0];   // [8,768,4096]
    const float* k = (const float*)d_in[1];   // [768,4096]
    float* y = (float*)d_out;

    // ws layout (28.6 MB; 45.1 MB proven available):
    unsigned short* T1 = (unsigned short*)d_ws;                 // [1024,4096] bf16
    unsigned short* T2 = T1 + (size_t)NF2 * LSEQ;               // [4096,1024] bf16
    unsigned short* AB = T2 + (size_t)LSEQ * NF2;               // [6144,1024] bf16

    // d_out doubles as scratch (85 MB of 100.66 MB) until stage B overwrites:
    unsigned short* Abm = (unsigned short*)d_out;               // [6912,4096] bf16, 56.6 MB
    float* C1 = (float*)((char*)d_out + (size_t)MROWS * LSEQ * 2); // [6912,1024] f32, 28.3 MB

    const int blk = 256;
    hipLaunchKernelGGL(build_tables, dim3(NF2 / 64, LSEQ / 64), dim3(blk), 0, stream, T1, T2);
    hipLaunchKernelGGL(tobf16, dim3((MROWS * LSEQ / 4) / blk), dim3(blk), 0, stream, x, k, Abm);
    // Stage A: [6912,4096] x [4096,1024] -> C1 (X and K spectra together)
    hipLaunchKernelGGL(gemm_bt, dim3(NF2 / 128, MROWS / 128), dim3(blk), 0, stream,
                       Abm, T1, C1, MROWS, NF2, LSEQ);
    hipLaunchKernelGGL(combine, dim3((NBH * NF) / blk), dim3(blk), 0, stream, C1, AB);
    // Stage B: [6144,1024] x [1024,4096] -> y
    hipLaunchKernelGGL(gemm_bt, dim3(LSEQ / 128, NBH / 128), dim3(blk), 0, stream,
                       AB, T2, y, NBH, LSEQ, NF2);
}

// Round 3
// 349.282 us; speedup vs baseline: 1.0209x; 1.0209x over previous
//
#include <hip/hip_runtime.h>
#include <math.h>

#define LSEQ 4096
#define NFFT 8192
#define NF   512     // kept frequency bins
#define NF2  1024    // 2*NF (cos/sin interleaved)
#define NH   768
#define NBH  6144    // 8*768
#define MROWS 6912   // NBH + NH (x rows + k rows share stage-A GEMM)
#define SPLIT_ROW 3456   // partial-1 row split (27*128: block-uniform)

typedef __attribute__((ext_vector_type(8))) short short8;   // 8 bf16 (4 VGPRs)
typedef __attribute__((ext_vector_type(4))) float floatx4;  // MFMA accumulator

__device__ __forceinline__ unsigned short f2bf(float f) {
    unsigned int u = __float_as_uint(f);
    u += 0x7fff + ((u >> 16) & 1);       // round-to-nearest-even
    return (unsigned short)(u >> 16);
}

// -------- fused trig tables: T1[f2][n] and T2[n][f2], bf16 -----------------
__global__ void build_tables(unsigned short* __restrict__ T1,
                             unsigned short* __restrict__ T2) {
    __shared__ unsigned short tile[64][66];   // pad 66: transpose-read conflict-free
    const int t = threadIdx.x;
    const int F0 = blockIdx.x * 64;
    const int N0 = blockIdx.y * 64;
#pragma unroll
    for (int i = 0; i < 16; ++i) {
        int r = (t >> 6) + i * 4;
        int c = t & 63;
        int f2 = F0 + r, n = N0 + c;
        int f = f2 >> 1;
        int p = (f * n) & (NFFT - 1);
        float th = (float)p * (float)(2.0 * M_PI / (double)NFFT);
        float s, cc;
        sincosf(th, &s, &cc);
        unsigned short v = f2bf((f2 & 1) ? s : cc);
        T1[(size_t)f2 * LSEQ + n] = v;
        tile[r][c] = v;
    }
    __syncthreads();
#pragma unroll
    for (int i = 0; i < 16; ++i) {
        int r = (t >> 6) + i * 4;
        int c = t & 63;
        T2[(size_t)(N0 + r) * NF2 + F0 + c] = tile[c][r];
    }
}

// -------- fp32 -> bf16 pack of [x ; k] into one [6912, 4096] matrix --------
__global__ void tobf16(const float* __restrict__ x, const float* __restrict__ kk,
                       unsigned short* __restrict__ o) {
    size_t e = ((size_t)blockIdx.x * 256 + threadIdx.x) * 4;
    const size_t XN = (size_t)NBH * LSEQ;
    const float* s = (e < XN) ? (x + e) : (kk + (e - XN));
    float4 v = *(const float4*)s;
    unsigned int lo = (unsigned int)f2bf(v.x) | ((unsigned int)f2bf(v.y) << 16);
    unsigned int hi = (unsigned int)f2bf(v.z) | ((unsigned int)f2bf(v.w) << 16);
    *(uint2*)(o + e) = make_uint2(lo, hi);
}

// -------- pipelined bf16 GEMM: C[M,N] = A[M,K] * B^T[N,K], fp32 out --------
// R1 reg-staging structure (proven 102us) + two changes for R3:
//  (1) split-K via blockIdx.z: z=0 -> C, z=1 -> partial (P1a/P1b, summed in
//      combine).  Stage A grid 432 -> 864 blocks (1.7 -> 3.4 resident/CU);
//      R1/R2 showed both pipes <33% at Occupancy 16% => latency-exposed.
//  (2) 2-deep register prefetch (two named reg sets, loop unrolled x2 --
//      static indexing only): ds_write of tile t+1 waits on loads that have
//      been in flight a FULL iteration, covering L2/L3 latency even on CUs
//      with a single resident block.
#define LOADSET(ra0, ra1, rb0, rb1, off)                      \
    ra0 = *(const uint4*)(pa0 + (off));                        \
    ra1 = *(const uint4*)(pa1 + (off));                        \
    rb0 = *(const uint4*)(pb0 + (off));                        \
    rb1 = *(const uint4*)(pb1 + (off));

#define WRITESET(buf, ra0, ra1, rb0, rb1)                      \
    *(uint4*)(As[buf] + q0 * 8) = ra0;                         \
    *(uint4*)(As[buf] + q1 * 8) = ra1;                         \
    *(uint4*)(Bs[buf] + q0 * 8) = rb0;                         \
    *(uint4*)(Bs[buf] + q1 * 8) = rb1;

#define COMPUTE(buf)                                                          \
    {                                                                         \
        short8 af[4], bfv[4];                                                 \
        _Pragma("unroll")                                                     \
        for (int i = 0; i < 4; ++i)                                           \
            af[i] = *(const short8*)(As[buf] + (wm + 16 * i + lr) * 32 + lq * 8); \
        _Pragma("unroll")                                                     \
        for (int j = 0; j < 4; ++j)                                           \
            bfv[j] = *(const short8*)(Bs[buf] + (wn + 16 * j + lr) * 32 + lq * 8); \
        _Pragma("unroll")                                                     \
        for (int i = 0; i < 4; ++i)                                           \
            _Pragma("unroll")                                                 \
            for (int j = 0; j < 4; ++j)                                       \
                acc[i][j] = __builtin_amdgcn_mfma_f32_16x16x32_bf16(          \
                    af[i], bfv[j], acc[i][j], 0, 0, 0);                       \
    }

__global__ __launch_bounds__(256) void gemm_bt(
    const unsigned short* __restrict__ A,   // [M,ldk] bf16
    const unsigned short* __restrict__ B,   // [N,ldk] bf16 (transposed operand)
    float* __restrict__ C,                  // [M,N] fp32 (z==0 target)
    float* __restrict__ P1a,                // z==1 target, rows < SPLIT_ROW
    float* __restrict__ P1b,                // z==1 target, rows >= SPLIT_ROW
    int M, int N, int ldk, int Ksub)        // Ksub: K-range per z-slice (mult of 64)
{
    __shared__ __align__(16) unsigned short As[2][128 * 32];
    __shared__ __align__(16) unsigned short Bs[2][128 * 32];
    const int t = threadIdx.x;
    const int w = t >> 6, l = t & 63;
    const int m0 = blockIdx.y * 128, n0 = blockIdx.x * 128;
    const int wm = (w >> 1) * 64, wn = (w & 1) * 64;
    const int lq = l >> 4, lr = l & 15;
    const int kbase = blockIdx.z * Ksub;

    floatx4 acc[4][4];
#pragma unroll
    for (int i = 0; i < 4; ++i)
#pragma unroll
        for (int j = 0; j < 4; ++j)
            acc[i][j] = (floatx4){0.f, 0.f, 0.f, 0.f};

    // staging: 2 x 16B chunks per operand per thread (8 KB tile / 256 thr)
    const int q0 = t, q1 = t + 256;
    const int r0 = q0 >> 2, e0 = (q0 & 3) * 8;
    const int r1 = q1 >> 2, e1 = (q1 & 3) * 8;
    const unsigned short* pa0 = A + (size_t)(m0 + r0) * ldk + e0 + kbase;
    const unsigned short* pa1 = A + (size_t)(m0 + r1) * ldk + e1 + kbase;
    const unsigned short* pb0 = B + (size_t)(n0 + r0) * ldk + e0 + kbase;
    const unsigned short* pb1 = B + (size_t)(n0 + r1) * ldk + e1 + kbase;

    uint4 xa0, xa1, xb0, xb1;   // reg set X (even tiles)
    uint4 ya0, ya1, yb0, yb1;   // reg set Y (odd tiles)

    // prologue: tile0 -> X -> buf0; tile1 -> Y (in flight)
    LOADSET(xa0, xa1, xb0, xb1, 0)
    WRITESET(0, xa0, xa1, xb0, xb1)
    LOADSET(ya0, ya1, yb0, yb1, 32)
    __syncthreads();

    const int T = Ksub >> 5;   // K-tiles; T even, >= 4 (64 or 32 here)
    for (int tt = 0; tt + 4 <= T; tt += 2) {
        // even half: compute tile tt (buf0); Y(tile tt+1) -> buf1; load tt+2 -> X
        LOADSET(xa0, xa1, xb0, xb1, (tt + 2) * 32)
        COMPUTE(0)
        WRITESET(1, ya0, ya1, yb0, yb1)   // vmcnt wait: Y loads, 1 full iter old
        __syncthreads();
        // odd half: compute tile tt+1 (buf1); X(tile tt+2) -> buf0; load tt+3 -> Y
        LOADSET(ya0, ya1, yb0, yb1, (tt + 3) * 32)
        COMPUTE(1)
        WRITESET(0, xa0, xa1, xb0, xb1)
        __syncthreads();
    }
    // tail: tiles T-2 (buf0) and T-1 (Y regs)
    COMPUTE(0)
    WRITESET(1, ya0, ya1, yb0, yb1)
    __syncthreads();
    COMPUTE(1)

    // epilogue target: z=0 -> C; z=1 -> partial (block-uniform row split)
    float* Cb;
    if (blockIdx.z == 0) {
        Cb = C;
    } else {
        Cb = (m0 < SPLIT_ROW) ? P1a : (P1b - (size_t)SPLIT_ROW * N);
    }
    // C/D layout: col = lane&15, row = (lane>>4)*4 + reg  [verified m89/m91]
#pragma unroll
    for (int i = 0; i < 4; ++i)
#pragma unroll
        for (int j = 0; j < 4; ++j)
#pragma unroll
            for (int r = 0; r < 4; ++r) {
                int row = m0 + wm + 16 * i + lq * 4 + r;
                int col = n0 + wn + 16 * j + lr;
                Cb[(size_t)row * N + col] = acc[i][j][r];
            }
}

// -------- combine: sum K-split partials + complex multiply + scaling -------
__global__ void combine(const float* __restrict__ C1,
                        const float* __restrict__ P1a,
                        const float* __restrict__ P1b,
                        unsigned short* __restrict__ AB) {
    int idx = blockIdx.x * blockDim.x + threadIdx.x;   // bh*512 + f
    int bh = idx >> 9;
    int f = idx & (NF - 1);
    int h = bh % NH;
    const float* xc = C1 + (size_t)bh * NF2 + 2 * f;
    const float* xp = (bh < SPLIT_ROW)
        ? (P1a + (size_t)bh * NF2 + 2 * f)
        : (P1b + (size_t)(bh - SPLIT_ROW) * NF2 + 2 * f);
    const int kr = NBH + h;    // always >= SPLIT_ROW
    const float* kc = C1 + (size_t)kr * NF2 + 2 * f;
    const float* kp = P1b + (size_t)(kr - SPLIT_ROW) * NF2 + 2 * f;
    float Xre = xc[0] + xp[0], Xim = -(xc[1] + xp[1]);
    float Kre = kc[0] + kp[0], Kim = -(kc[1] + kp[1]);
    float s = (f == 0 ? 1.0f : 2.0f) * (1.0f / (float)NFFT);
    float Av = s * (Xre * Kre - Xim * Kim);
    float Bv = -(s * (Xre * Kim + Xim * Kre));
    unsigned int packed = (unsigned int)f2bf(Av) | ((unsigned int)f2bf(Bv) << 16);
    *(unsigned int*)(AB + (size_t)bh * NF2 + 2 * f) = packed;
}

extern "C" void kernel_launch(void* const* d_in, const int* in_sizes, int n_in,
                              void* d_out, int out_size, void* d_ws, size_t ws_size,
                              hipStream_t stream) {
    const float* x = (const float*)d_in[0];   // [8,768,4096]
    const float* k = (const float*)d_in[1];   // [768,4096]
    float* y = (float*)d_out;

    // ws layout (43.5 MB of 45.1 MB proven):
    unsigned short* T1 = (unsigned short*)d_ws;                 // [1024,4096] bf16,  8.39 MB
    unsigned short* T2 = T1 + (size_t)NF2 * LSEQ;               // [4096,1024] bf16,  8.39 MB
    unsigned short* AB = T2 + (size_t)LSEQ * NF2;               // [6144,1024] bf16, 12.58 MB
    float* P1a = (float*)(AB + (size_t)NBH * NF2);              // [3456,1024] f32,  14.16 MB

    // d_out doubles as scratch (99.1 MB of 100.66 MB) until stage B overwrites:
    unsigned short* Abm = (unsigned short*)d_out;               // [6912,4096] bf16, 56.62 MB
    float* C1 = (float*)((char*)d_out + (size_t)MROWS * LSEQ * 2); // [6912,1024] f32, 28.31 MB
    float* P1b = C1 + (size_t)MROWS * NF2;                      // [3456,1024] f32,  14.16 MB

    const int blk = 256;
    hipLaunchKernelGGL(build_tables, dim3(NF2 / 64, LSEQ / 64), dim3(blk), 0, stream, T1, T2);
    hipLaunchKernelGGL(tobf16, dim3((MROWS * LSEQ / 4) / blk), dim3(blk), 0, stream, x, k, Abm);
    // Stage A: [6912,4096] x [4096,1024], split-K x2 -> C1 (z=0) + P1 (z=1)
    hipLaunchKernelGGL(gemm_bt, dim3(NF2 / 128, MROWS / 128, 2), dim3(blk), 0, stream,
                       Abm, T1, C1, P1a, P1b, MROWS, NF2, LSEQ, LSEQ / 2);
    hipLaunchKernelGGL(combine, dim3((NBH * NF) / blk), dim3(blk), 0, stream, C1, P1a, P1b, AB);
    // Stage B: [6144,1024] x [1024,4096] -> y (no split)
    hipLaunchKernelGGL(gemm_bt, dim3(LSEQ / 128, NBH / 128, 1), dim3(blk), 0, stream,
                       AB, T2, y, (float*)nullptr, (float*)nullptr, NBH, LSEQ, NF2, NF2);
}

// Round 4
// 343.015 us; speedup vs baseline: 1.0396x; 1.0183x over previous
//
#include <hip/hip_runtime.h>
#include <math.h>

#define LSEQ 4096
#define NFFT 8192
#define NF   512     // kept frequency bins
#define NF2  1024    // 2*NF (cos/sin interleaved)
#define NH   768
#define NBH  6144    // 8*768
#define MROWS 6912   // NBH + NH (x rows + k rows share stage-A GEMM)
#define SPLIT_ROW 3456   // partial-1 row split (27*128: block-uniform)

typedef __attribute__((ext_vector_type(8))) short short8;   // 8 bf16 (4 VGPRs)
typedef __attribute__((ext_vector_type(4))) float floatx4;  // MFMA accumulator

__device__ __forceinline__ unsigned short f2bf(float f) {
    unsigned int u = __float_as_uint(f);
    u += 0x7fff + ((u >> 16) & 1);       // round-to-nearest-even
    return (unsigned short)(u >> 16);
}

// -------- fused trig tables: T1[f2][n] and T2[n][f2], bf16 -----------------
__global__ void build_tables(unsigned short* __restrict__ T1,
                             unsigned short* __restrict__ T2) {
    __shared__ unsigned short tile[64][66];   // pad 66: transpose-read conflict-free
    const int t = threadIdx.x;
    const int F0 = blockIdx.x * 64;
    const int N0 = blockIdx.y * 64;
#pragma unroll
    for (int i = 0; i < 16; ++i) {
        int r = (t >> 6) + i * 4;
        int c = t & 63;
        int f2 = F0 + r, n = N0 + c;
        int f = f2 >> 1;
        int p = (f * n) & (NFFT - 1);
        float th = (float)p * (float)(2.0 * M_PI / (double)NFFT);
        float s, cc;
        sincosf(th, &s, &cc);
        unsigned short v = f2bf((f2 & 1) ? s : cc);
        T1[(size_t)f2 * LSEQ + n] = v;
        tile[r][c] = v;
    }
    __syncthreads();
#pragma unroll
    for (int i = 0; i < 16; ++i) {
        int r = (t >> 6) + i * 4;
        int c = t & 63;
        T2[(size_t)(N0 + r) * NF2 + F0 + c] = tile[c][r];
    }
}

// -------- fp32 -> bf16 pack of [x ; k] into one [6912, 4096] matrix --------
__global__ void tobf16(const float* __restrict__ x, const float* __restrict__ kk,
                       unsigned short* __restrict__ o) {
    size_t e = ((size_t)blockIdx.x * 256 + threadIdx.x) * 4;
    const size_t XN = (size_t)NBH * LSEQ;
    const float* s = (e < XN) ? (x + e) : (kk + (e - XN));
    float4 v = *(const float4*)s;
    unsigned int lo = (unsigned int)f2bf(v.x) | ((unsigned int)f2bf(v.y) << 16);
    unsigned int hi = (unsigned int)f2bf(v.z) | ((unsigned int)f2bf(v.w) << 16);
    *(uint2*)(o + e) = make_uint2(lo, hi);
}

// -------- pipelined bf16 GEMM: C[M,N] = A[M,K] * B^T[N,K], fp32 out --------
// R3 counters: stage-A FETCH=228MB vs 65MB ideal == A re-fetched by each of
// the 8 column-blocks (they round-robin onto 8 different XCD L2s), and
// dur ~= traffic / achieved-BW.  R4 fix: flat 1-D grid + chunked bijective
// XCD swizzle (T1): swz=(bid&7)*(nwg/8)+(bid>>3) gives each XCD a contiguous
// work chunk, so the 8 blocks sharing an A-panel run on ONE XCD -> panel hits
// its L2.  Keeps R3's split-K x2 + 2-deep register prefetch.
#define LOADSET(ra0, ra1, rb0, rb1, off)                      \
    ra0 = *(const uint4*)(pa0 + (off));                        \
    ra1 = *(const uint4*)(pa1 + (off));                        \
    rb0 = *(const uint4*)(pb0 + (off));                        \
    rb1 = *(const uint4*)(pb1 + (off));

#define WRITESET(buf, ra0, ra1, rb0, rb1)                      \
    *(uint4*)(As[buf] + q0 * 8) = ra0;                         \
    *(uint4*)(As[buf] + q1 * 8) = ra1;                         \
    *(uint4*)(Bs[buf] + q0 * 8) = rb0;                         \
    *(uint4*)(Bs[buf] + q1 * 8) = rb1;

#define COMPUTE(buf)                                                          \
    {                                                                         \
        short8 af[4], bfv[4];                                                 \
        _Pragma("unroll")                                                     \
        for (int i = 0; i < 4; ++i)                                           \
            af[i] = *(const short8*)(As[buf] + (wm + 16 * i + lr) * 32 + lq * 8); \
        _Pragma("unroll")                                                     \
        for (int j = 0; j < 4; ++j)                                           \
            bfv[j] = *(const short8*)(Bs[buf] + (wn + 16 * j + lr) * 32 + lq * 8); \
        _Pragma("unroll")                                                     \
        for (int i = 0; i < 4; ++i)                                           \
            _Pragma("unroll")                                                 \
            for (int j = 0; j < 4; ++j)                                       \
                acc[i][j] = __builtin_amdgcn_mfma_f32_16x16x32_bf16(          \
                    af[i], bfv[j], acc[i][j], 0, 0, 0);                       \
    }

__global__ __launch_bounds__(256) void gemm_bt(
    const unsigned short* __restrict__ A,   // [M,ldk] bf16
    const unsigned short* __restrict__ B,   // [N,ldk] bf16 (transposed operand)
    float* __restrict__ C,                  // [M,N] fp32 (z==0 target)
    float* __restrict__ P1a,                // z==1 target, rows < SPLIT_ROW
    float* __restrict__ P1b,                // z==1 target, rows >= SPLIT_ROW
    int gx, int gy,                          // logical grid (cols, rows); flat 1-D launch
    int N, int ldk, int Ksub)               // Ksub: K-range per z-slice
{
    __shared__ __align__(16) unsigned short As[2][128 * 32];
    __shared__ __align__(16) unsigned short Bs[2][128 * 32];
    const int t = threadIdx.x;
    const int w = t >> 6, l = t & 63;

    // chunked bijective XCD swizzle (nwg % 8 == 0 for both stages: 864, 1536)
    const int nwg = gridDim.x;
    const int bid = blockIdx.x;
    const int swz = (bid & 7) * (nwg >> 3) + (bid >> 3);
    const int bx = swz % gx;
    const int rem = swz / gx;
    const int by = rem % gy;
    const int bz = rem / gy;

    const int m0 = by * 128, n0 = bx * 128;
    const int wm = (w >> 1) * 64, wn = (w & 1) * 64;
    const int lq = l >> 4, lr = l & 15;
    const int kbase = bz * Ksub;

    floatx4 acc[4][4];
#pragma unroll
    for (int i = 0; i < 4; ++i)
#pragma unroll
        for (int j = 0; j < 4; ++j)
            acc[i][j] = (floatx4){0.f, 0.f, 0.f, 0.f};

    // staging: 2 x 16B chunks per operand per thread (8 KB tile / 256 thr)
    const int q0 = t, q1 = t + 256;
    const int r0 = q0 >> 2, e0 = (q0 & 3) * 8;
    const int r1 = q1 >> 2, e1 = (q1 & 3) * 8;
    const unsigned short* pa0 = A + (size_t)(m0 + r0) * ldk + e0 + kbase;
    const unsigned short* pa1 = A + (size_t)(m0 + r1) * ldk + e1 + kbase;
    const unsigned short* pb0 = B + (size_t)(n0 + r0) * ldk + e0 + kbase;
    const unsigned short* pb1 = B + (size_t)(n0 + r1) * ldk + e1 + kbase;

    uint4 xa0, xa1, xb0, xb1;   // reg set X (even tiles)
    uint4 ya0, ya1, yb0, yb1;   // reg set Y (odd tiles)

    // prologue: tile0 -> X -> buf0; tile1 -> Y (in flight)
    LOADSET(xa0, xa1, xb0, xb1, 0)
    WRITESET(0, xa0, xa1, xb0, xb1)
    LOADSET(ya0, ya1, yb0, yb1, 32)
    __syncthreads();

    const int T = Ksub >> 5;   // K-tiles; T even, >= 4 (64 or 32 here)
    for (int tt = 0; tt + 4 <= T; tt += 2) {
        // even half: compute tile tt (buf0); Y(tile tt+1) -> buf1; load tt+2 -> X
        LOADSET(xa0, xa1, xb0, xb1, (tt + 2) * 32)
        COMPUTE(0)
        WRITESET(1, ya0, ya1, yb0, yb1)   // vmcnt wait: Y loads, 1 full iter old
        __syncthreads();
        // odd half: compute tile tt+1 (buf1); X(tile tt+2) -> buf0; load tt+3 -> Y
        LOADSET(ya0, ya1, yb0, yb1, (tt + 3) * 32)
        COMPUTE(1)
        WRITESET(0, xa0, xa1, xb0, xb1)
        __syncthreads();
    }
    // tail: tiles T-2 (buf0) and T-1 (Y regs)
    COMPUTE(0)
    WRITESET(1, ya0, ya1, yb0, yb1)
    __syncthreads();
    COMPUTE(1)

    // epilogue target: z=0 -> C; z=1 -> partial (block-uniform row split)
    float* Cb;
    if (bz == 0) {
        Cb = C;
    } else {
        Cb = (m0 < SPLIT_ROW) ? P1a : (P1b - (size_t)SPLIT_ROW * N);
    }
    // C/D layout: col = lane&15, row = (lane>>4)*4 + reg  [verified m89/m91]
#pragma unroll
    for (int i = 0; i < 4; ++i)
#pragma unroll
        for (int j = 0; j < 4; ++j)
#pragma unroll
            for (int r = 0; r < 4; ++r) {
                int row = m0 + wm + 16 * i + lq * 4 + r;
                int col = n0 + wn + 16 * j + lr;
                Cb[(size_t)row * N + col] = acc[i][j][r];
            }
}

// -------- combine: sum K-split partials + complex multiply + scaling -------
__global__ void combine(const float* __restrict__ C1,
                        const float* __restrict__ P1a,
                        const float* __restrict__ P1b,
                        unsigned short* __restrict__ AB) {
    int idx = blockIdx.x * blockDim.x + threadIdx.x;   // bh*512 + f
    int bh = idx >> 9;
    int f = idx & (NF - 1);
    int h = bh % NH;
    const float* xc = C1 + (size_t)bh * NF2 + 2 * f;
    const float* xp = (bh < SPLIT_ROW)
        ? (P1a + (size_t)bh * NF2 + 2 * f)
        : (P1b + (size_t)(bh - SPLIT_ROW) * NF2 + 2 * f);
    const int kr = NBH + h;    // always >= SPLIT_ROW
    const float* kc = C1 + (size_t)kr * NF2 + 2 * f;
    const float* kp = P1b + (size_t)(kr - SPLIT_ROW) * NF2 + 2 * f;
    float Xre = xc[0] + xp[0], Xim = -(xc[1] + xp[1]);
    float Kre = kc[0] + kp[0], Kim = -(kc[1] + kp[1]);
    float s = (f == 0 ? 1.0f : 2.0f) * (1.0f / (float)NFFT);
    float Av = s * (Xre * Kre - Xim * Kim);
    float Bv = -(s * (Xre * Kim + Xim * Kre));
    unsigned int packed = (unsigned int)f2bf(Av) | ((unsigned int)f2bf(Bv) << 16);
    *(unsigned int*)(AB + (size_t)bh * NF2 + 2 * f) = packed;
}

extern "C" void kernel_launch(void* const* d_in, const int* in_sizes, int n_in,
                              void* d_out, int out_size, void* d_ws, size_t ws_size,
                              hipStream_t stream) {
    const float* x = (const float*)d_in[0];   // [8,768,4096]
    const float* k = (const float*)d_in[1];   // [768,4096]
    float* y = (float*)d_out;

    // ws layout (43.5 MB of 45.1 MB proven):
    unsigned short* T1 = (unsigned short*)d_ws;                 // [1024,4096] bf16,  8.39 MB
    unsigned short* T2 = T1 + (size_t)NF2 * LSEQ;               // [4096,1024] bf16,  8.39 MB
    unsigned short* AB = T2 + (size_t)LSEQ * NF2;               // [6144,1024] bf16, 12.58 MB
    float* P1a = (float*)(AB + (size_t)NBH * NF2);              // [3456,1024] f32,  14.16 MB

    // d_out doubles as scratch (99.1 MB of 100.66 MB) until stage B overwrites:
    unsigned short* Abm = (unsigned short*)d_out;               // [6912,4096] bf16, 56.62 MB
    float* C1 = (float*)((char*)d_out + (size_t)MROWS * LSEQ * 2); // [6912,1024] f32, 28.31 MB
    float* P1b = C1 + (size_t)MROWS * NF2;                      // [3456,1024] f32,  14.16 MB

    const int blk = 256;
    hipLaunchKernelGGL(build_tables, dim3(NF2 / 64, LSEQ / 64), dim3(blk), 0, stream, T1, T2);
    hipLaunchKernelGGL(tobf16, dim3((MROWS * LSEQ / 4) / blk), dim3(blk), 0, stream, x, k, Abm);
    // Stage A: [6912,4096] x [4096,1024], split-K x2, flat grid 8*54*2=864
    hipLaunchKernelGGL(gemm_bt, dim3(8 * 54 * 2), dim3(blk), 0, stream,
                       Abm, T1, C1, P1a, P1b, 8, 54, NF2, LSEQ, LSEQ / 2);
    hipLaunchKernelGGL(combine, dim3((NBH * NF) / blk), dim3(blk), 0, stream, C1, P1a, P1b, AB);
    // Stage B: [6144,1024] x [1024,4096] -> y, flat grid 32*48=1536
    hipLaunchKernelGGL(gemm_bt, dim3(32 * 48), dim3(blk), 0, stream,
                       AB, T2, y, (float*)nullptr, (float*)nullptr, 32, 48, LSEQ, NF2, NF2);
}